// Round 10
// baseline (32287.918 us; speedup 1.0000x reference)
//
#include <hip/hip_runtime.h>

namespace {
constexpr int kB  = 32;
constexpr int kT  = 1024;
constexpr int kD  = 512;
constexpr int kH  = 1024;
constexpr int kLV = 128;
constexpr int kNG = 4 * kH + 2 * kLV;   // 4352
constexpr int kNBLK = 256;
constexpr int kNTHR = 512;
constexpr int kCPB  = 34;               // 32 lstm + 2 lvl cols per A-block
// ws float offsets
constexpr int kOffH0 = 8192;
constexpr int kOffWF = kOffH0 + 2 * kB * kH + 2 * kB * kNG;
}

typedef float vfloat4 __attribute__((ext_vector_type(4)));
typedef _Float16 half2_t __attribute__((ext_vector_type(2)));
typedef _Float16 half8_t __attribute__((ext_vector_type(8)));
typedef unsigned short ushort_t;

static __device__ __forceinline__ unsigned ld_flag(const unsigned* p) {
  return __hip_atomic_load(p, __ATOMIC_RELAXED, __HIP_MEMORY_SCOPE_AGENT);
}
static __device__ __forceinline__ void st_flag(unsigned* p, unsigned v) {
  __hip_atomic_store(p, v, __ATOMIC_RELAXED, __HIP_MEMORY_SCOPE_AGENT);
}
static __device__ __forceinline__ float ld_coh(const float* p) {
  return __hip_atomic_load(p, __ATOMIC_RELAXED, __HIP_MEMORY_SCOPE_AGENT);
}
// write-through store to the coherent point (no dirty-L2 state)
static __device__ __forceinline__ void st_wt(float* p, float v) {
  asm volatile("global_store_dword %0, %1, off sc0 sc1" :: "v"(p), "v"(v) : "memory");
}
// 16 coherent 16B loads (two 512-col segments), overlapped, completed INSIDE
// one asm block (no in-flight asm outputs across compiler-visible code).
static __device__ __forceinline__ void ld_sc_x16(vfloat4 v[16],
                                                 const float* b0, const float* b1) {
  asm volatile(
      "global_load_dwordx4 %0,  %16, off sc0 sc1\n\t"
      "global_load_dwordx4 %1,  %16, off offset:16 sc0 sc1\n\t"
      "global_load_dwordx4 %2,  %16, off offset:32 sc0 sc1\n\t"
      "global_load_dwordx4 %3,  %16, off offset:48 sc0 sc1\n\t"
      "global_load_dwordx4 %4,  %16, off offset:64 sc0 sc1\n\t"
      "global_load_dwordx4 %5,  %16, off offset:80 sc0 sc1\n\t"
      "global_load_dwordx4 %6,  %16, off offset:96 sc0 sc1\n\t"
      "global_load_dwordx4 %7,  %16, off offset:112 sc0 sc1\n\t"
      "global_load_dwordx4 %8,  %17, off sc0 sc1\n\t"
      "global_load_dwordx4 %9,  %17, off offset:16 sc0 sc1\n\t"
      "global_load_dwordx4 %10, %17, off offset:32 sc0 sc1\n\t"
      "global_load_dwordx4 %11, %17, off offset:48 sc0 sc1\n\t"
      "global_load_dwordx4 %12, %17, off offset:64 sc0 sc1\n\t"
      "global_load_dwordx4 %13, %17, off offset:80 sc0 sc1\n\t"
      "global_load_dwordx4 %14, %17, off offset:96 sc0 sc1\n\t"
      "global_load_dwordx4 %15, %17, off offset:112 sc0 sc1\n\t"
      "s_waitcnt vmcnt(0)"
      : "=&v"(v[0]), "=&v"(v[1]), "=&v"(v[2]), "=&v"(v[3]),
        "=&v"(v[4]), "=&v"(v[5]), "=&v"(v[6]), "=&v"(v[7]),
        "=&v"(v[8]), "=&v"(v[9]), "=&v"(v[10]), "=&v"(v[11]),
        "=&v"(v[12]), "=&v"(v[13]), "=&v"(v[14]), "=&v"(v[15])
      : "v"(b0), "v"(b1)
      : "memory");
}
static __device__ __forceinline__ float fdot2(unsigned a, unsigned b, float c) {
  return __builtin_amdgcn_fdot2(__builtin_bit_cast(half2_t, a),
                                __builtin_bit_cast(half2_t, b), c, false);
}
static __device__ __forceinline__ unsigned pkrtz(float a, float b) {
  return __builtin_bit_cast(unsigned, __builtin_amdgcn_cvt_pkrtz(a, b));
}

// -------- fp32 -> fp16 weight conversion (one-time pre-pass) --------
__global__ __launch_bounds__(256) void cvt_fp16_kernel(
    const float* __restrict__ src, ushort_t* __restrict__ dst, int n8) {
  int i = blockIdx.x * 256 + threadIdx.x;
  if (i >= n8) return;
  const vfloat4* s4 = (const vfloat4*)src;
  vfloat4 a = s4[2 * i], b = s4[2 * i + 1];
  half8_t o;
  o[0] = (_Float16)a.x; o[1] = (_Float16)a.y;
  o[2] = (_Float16)a.z; o[3] = (_Float16)a.w;
  o[4] = (_Float16)b.x; o[5] = (_Float16)b.y;
  o[6] = (_Float16)b.z; o[7] = (_Float16)b.w;
  ((half8_t*)dst)[i] = o;
}

__global__ __launch_bounds__(kNTHR, 2) void onlstm_kernel(
    const float* __restrict__ x,
    const float* __restrict__ bl0, const float* __restrict__ bv0,
    const float* __restrict__ bl1, const float* __restrict__ bv1,
    const ushort_t* __restrict__ wf0u, const ushort_t* __restrict__ wf1u,
    float* __restrict__ out, float* __restrict__ ws)
{
  const int tid = threadIdx.x;
  const int bid = blockIdx.x;

  // ---- workspace ----
  unsigned* flags = (unsigned*)ws;            // [256] stride-16 uints
  unsigned* genp  = (unsigned*)ws + 4096;
  float* h0     = ws + kOffH0;                // [32][1024]
  float* h1     = h0 + kB * kH;
  float* gates0 = h1 + kB * kH;               // [32][4352]
  float* gates1 = gates0 + kB * kNG;

  // LDS: weights as 16B granules, permuted (p = j*16 + s within each 512-k seg)
  __shared__ uint4 wlds4[kCPB * 256];         // 139,264 B
  __shared__ float gst[kB][37];               // gate-store bounce (pad 37)
  __shared__ float ih_sh[kLV], fh_sh[kLV];
  __shared__ float smx[8];

  unsigned seq = 0;
  // flags-only barrier (proven r8/r9)
  auto gridbar = [&]() {
    ++seq;
    asm volatile("s_waitcnt vmcnt(0)" ::: "memory");
    __syncthreads();
    if (bid == 0) {
      if (tid >= 1 && tid < kNBLK) {
        while (ld_flag(&flags[tid * 16]) != seq) __builtin_amdgcn_s_sleep(2);
      }
      __syncthreads();
      if (tid == 0) st_flag(genp, seq);
    } else {
      if (tid == 0) {
        st_flag(&flags[bid * 16], seq);
        while (ld_flag(genp) != seq) __builtin_amdgcn_s_sleep(2);
      }
      __syncthreads();
    }
    asm volatile("" ::: "memory");
  };

  // ---- roles ----
  const int role = bid >> 7;                  // 0: layer0 GEMM (+ALL cell B), 1: layer1 GEMM
  const int g    = bid & 127;
  const int K    = role ? 2048 : 1536;
  const int ngr  = K >> 3;                    // 16B granules per col (256/192)
  const float* bl = role ? bl1 : bl0;
  const float* bv = role ? bv1 : bv0;
  float* gates = role ? gates1 : gates0;
  const ushort_t* wf = role ? wf1u : wf0u;

  const int s_  = tid & 15;                   // K-slice within 512-seg (32 floats)
  const int row = tid >> 4;                   // batch row 0..31
  const int pb  = g >> 2;                     // phase-B row
  const int qq4 = g & 3;                      // phase-B col quarter

  // ---- one-time: weights global(fp16) -> LDS, granule-permuted ----
  {
    for (int cc = 0; cc < kCPB; ++cc) {
      int jcol = (cc < 32) ? (g * 32 + cc) : (4096 + g * 2 + (cc - 32));
      const uint4* src = (const uint4*)(wf + (size_t)jcol * K);
      for (int kg = tid; kg < ngr; kg += kNTHR) {
        int si = kg >> 6, kgs = kg & 63;
        int s2 = kgs >> 2, j2 = kgs & 3;
        wlds4[cc * ngr + (si << 6) + (j2 << 4) + s2] = src[kg];
      }
    }
    __syncthreads();
  }

  // zero h0,h1 (write-through)
  {
    int idx = bid * kNTHR + tid;
    if (idx < 2 * kB * kH) st_wt(h0 + idx, 0.f);
  }
  float creg0 = 0.f, creg1 = 0.f;
  gridbar();

  float acc[kCPB];
  uint4 cmb[8];

  // FMA one 512-k segment against cm[0..3] (32 packed halfs)
  auto do_seg = [&](int si, const uint4* cm) {
    const uint4* wp0 = &wlds4[(si << 6) + s_];
#pragma unroll
    for (int cc = 0; cc < kCPB; ++cc) {
      const uint4* wp = wp0 + cc * ngr;
      uint4 w0 = wp[0], w1 = wp[16], w2 = wp[32], w3 = wp[48];
      float a = acc[cc];
      a = fdot2(cm[0].x, w0.x, a); a = fdot2(cm[0].y, w0.y, a);
      a = fdot2(cm[0].z, w0.z, a); a = fdot2(cm[0].w, w0.w, a);
      a = fdot2(cm[1].x, w1.x, a); a = fdot2(cm[1].y, w1.y, a);
      a = fdot2(cm[1].z, w1.z, a); a = fdot2(cm[1].w, w1.w, a);
      a = fdot2(cm[2].x, w2.x, a); a = fdot2(cm[2].y, w2.y, a);
      a = fdot2(cm[2].z, w2.z, a); a = fdot2(cm[2].w, w2.w, a);
      a = fdot2(cm[3].x, w3.x, a); a = fdot2(cm[3].y, w3.y, a);
      a = fdot2(cm[3].z, w3.z, a); a = fdot2(cm[3].w, w3.w, a);
      acc[cc] = a;
    }
  };
  // pack 8 vfloat4 (one segment) into cm[0..3]
  auto pack4 = [&](const vfloat4* v, uint4* cm) {
#pragma unroll
    for (int j = 0; j < 4; ++j) {
      cm[j].x = pkrtz(v[2 * j].x, v[2 * j].y);
      cm[j].y = pkrtz(v[2 * j].z, v[2 * j].w);
      cm[j].z = pkrtz(v[2 * j + 1].x, v[2 * j + 1].y);
      cm[j].w = pkrtz(v[2 * j + 1].z, v[2 * j + 1].w);
    }
  };

  // cell update (phase B) for one layer at (pb, qq4); cr = c-state register
  auto cellB = [&](const float* gbase, float* hb, float& cr, float* outp, int t) {
    const float* gr = gbase + (size_t)pb * kNG;
    const int lane = tid & 63, wv2 = tid >> 6;
    const bool sm = tid < 128;
    const bool cl = tid < 256;

    float vi = 0.f, vf = 0.f, vo = 0.f, vg = 0.f;
    int j = qq4 * 256 + tid;
    if (cl) {                                 // hoisted: latency under softmax
      vi = ld_coh(gr + j);
      vf = ld_coh(gr + kH + j);
      vo = ld_coh(gr + 2 * kH + j);
      vg = ld_coh(gr + 3 * kH + j);
    }
    float ai = 0.f, af = 0.f;
    if (sm) { ai = ld_coh(gr + 4096 + tid); af = ld_coh(gr + 4096 + kLV + tid); }
    float mi = ai, mf = af;
    if (sm) {
#pragma unroll
      for (int d2 = 32; d2 > 0; d2 >>= 1) {
        mi = fmaxf(mi, __shfl_xor(mi, d2));
        mf = fmaxf(mf, __shfl_xor(mf, d2));
      }
      if (lane == 0) { smx[wv2] = mi; smx[2 + wv2] = mf; }
    }
    __syncthreads();
    mi = fmaxf(smx[0], smx[1]);
    mf = fmaxf(smx[2], smx[3]);
    float ei = 0.f, Pi = 0.f, Pf = 0.f;
    if (sm) {
      ei = __expf(ai - mi);
      float ef = __expf(af - mf);
      Pi = ei; Pf = ef;
#pragma unroll
      for (int d2 = 1; d2 < 64; d2 <<= 1) {
        float ni = __shfl_up(Pi, d2);
        float nf = __shfl_up(Pf, d2);
        if (lane >= d2) { Pi += ni; Pf += nf; }
      }
      if (lane == 63) { smx[4 + wv2] = Pi; smx[6 + wv2] = Pf; }
    }
    __syncthreads();
    float Si = smx[4] + smx[5], Sf = smx[6] + smx[7];
    if (sm) {
      if (wv2 == 1) { Pi += smx[4]; Pf += smx[6]; }
      ih_sh[tid] = Pf / Sf;                   // cumsum(softmax(cc_f_h))
      fh_sh[tid] = (Si - Pi + ei) / Si;       // rev-cumsum(softmax(rev cc_i_h))
    }
    __syncthreads();
    if (cl) {
      float i_ = 1.f / (1.f + __expf(-vi));
      float f_ = 1.f / (1.f + __expf(-vf));
      float o_ = 1.f / (1.f + __expf(-vo));
      float g_ = tanhf(vg);
      int l2 = j >> 3;
      float ih = ih_sh[l2], fh = fh_sh[l2];
      float w  = ih * fh;
      float cold = cr;
      float cn = w * (f_ * cold + i_ * g_) + (fh - w) * cold + (ih - w) * g_;
      float hn = o_ * tanhf(cn);
      cr = cn;
      st_wt(hb + (size_t)pb * kH + j, hn);
      if (outp) st_wt(outp + ((size_t)pb * kT + t) * kH + j, hn);
    }
  };

  for (int e = 0; e <= kT; ++e) {
    const bool actA = (role == 0) ? (e < kT) : (e >= 1);
    const int t = (role == 0) ? e : e - 1;

    // ========== Phase A: gates = [x_t, h] @ W^T + b ==========
    if (actA) {
#pragma unroll
      for (int cc = 0; cc < kCPB; ++cc) acc[cc] = 0.f;
      vfloat4 v[16];
      if (role == 0) {
        // seg 0: x (immutable -> plain cached loads)
        const float* px = x + ((size_t)row * kT + t) * kD + s_ * 32;
#pragma unroll
        for (int i = 0; i < 8; ++i) v[i] = *(const vfloat4*)(px + i * 4);
        pack4(v, cmb); do_seg(0, cmb);
        // segs 1,2: h0 (one batched coherent x16)
        ld_sc_x16(v, h0 + (size_t)row * kH + s_ * 32,
                     h0 + (size_t)row * kH + 512 + s_ * 32);
        pack4(v, cmb); pack4(v + 8, cmb + 4);
        do_seg(1, cmb); do_seg(2, cmb + 4);
      } else {
        // segs 0,1: h0(t) (was 'out'; identical data, one x16)
        ld_sc_x16(v, h0 + (size_t)row * kH + s_ * 32,
                     h0 + (size_t)row * kH + 512 + s_ * 32);
        pack4(v, cmb); pack4(v + 8, cmb + 4);
        do_seg(0, cmb); do_seg(1, cmb + 4);
        // segs 2,3: h1 (one x16)
        ld_sc_x16(v, h1 + (size_t)row * kH + s_ * 32,
                     h1 + (size_t)row * kH + 512 + s_ * 32);
        pack4(v, cmb); pack4(v + 8, cmb + 4);
        do_seg(2, cmb); do_seg(3, cmb + 4);
      }
      // in-wave reduce over the 16 K-slices (s = lane bits 0..3)
#pragma unroll
      for (int cc = 0; cc < kCPB; ++cc) {
        float a = acc[cc];
        a += __shfl_xor(a, 1);
        a += __shfl_xor(a, 2);
        a += __shfl_xor(a, 4);
        a += __shfl_xor(a, 8);
        acc[cc] = a;
      }
      // bounce through LDS -> lane-coalesced write-through stores (r9 fix)
      if (s_ == 0) {
#pragma unroll
        for (int cc = 0; cc < kCPB; ++cc) gst[row][cc] = acc[cc];
      }
      __syncthreads();
      for (int o = tid; o < kB * kCPB; o += kNTHR) {
        int r2 = o / kCPB;
        int cc = o - r2 * kCPB;
        int j = (cc < 32) ? (g * 32 + cc) : (4096 + g * 2 + (cc - 32));
        float bias = (cc < 32) ? bl[g * 32 + cc] : bv[g * 2 + (cc - 32)];
        st_wt(gates + (size_t)r2 * kNG + j, gst[r2][cc] + bias);
      }
    }
    gridbar();

    // ========== Phase B: role0 blocks own BOTH layers' cell updates ==========
    // (role1 blocks skip B entirely -> role workloads balance: role1's longer
    //  GEMM overlaps role0's double cell update)
    if (role == 0) {
      if (e < kT) cellB(gates0, h0, creg0, nullptr, e);       // layer 0, t=e
      __syncthreads();
      if (e >= 1) cellB(gates1, h1, creg1, out, e - 1);       // layer 1, t=e-1
    }
    gridbar();
  }
}

extern "C" void kernel_launch(void* const* d_in, const int* in_sizes, int n_in,
                              void* d_out, int out_size, void* d_ws, size_t ws_size,
                              hipStream_t stream) {
  const float* x   = (const float*)d_in[0];
  const float* Wl0 = (const float*)d_in[1];
  const float* bl0 = (const float*)d_in[2];
  const float* Wv0 = (const float*)d_in[3];
  const float* bv0 = (const float*)d_in[4];
  const float* Wl1 = (const float*)d_in[5];
  const float* bl1 = (const float*)d_in[6];
  const float* Wv1 = (const float*)d_in[7];
  const float* bv1 = (const float*)d_in[8];
  (void)in_sizes; (void)n_in; (void)out_size; (void)ws_size;

  float* ws = (float*)d_ws;
  ushort_t* wf0 = (ushort_t*)(ws + kOffWF);                 // [4352][1536] fp16
  ushort_t* wf1 = wf0 + (size_t)4352 * 1536;                // [4352][2048] fp16

  // pre-pass: convert weights to fp16 (Wl then Wv rows, per layer)
  {
    int n;
    n = 4096 * 1536 / 8;
    cvt_fp16_kernel<<<(n + 255) / 256, 256, 0, stream>>>(Wl0, wf0, n);
    n = 256 * 1536 / 8;
    cvt_fp16_kernel<<<(n + 255) / 256, 256, 0, stream>>>(
        Wv0, wf0 + (size_t)4096 * 1536, n);
    n = 4096 * 2048 / 8;
    cvt_fp16_kernel<<<(n + 255) / 256, 256, 0, stream>>>(Wl1, wf1, n);
    n = 256 * 2048 / 8;
    cvt_fp16_kernel<<<(n + 255) / 256, 256, 0, stream>>>(
        Wv1, wf1 + (size_t)4096 * 2048, n);
  }

  onlstm_kernel<<<dim3(kNBLK), dim3(kNTHR), 0, stream>>>(
      x, bl0, bv0, bl1, bv1, wf0, wf1, (float*)d_out, ws);
}